// Round 11
// baseline (154.773 us; speedup 1.0000x reference)
//
#include <hip/hip_runtime.h>
#include <math.h>

#define NPTS 16384
#define DIN 13
#define KNN 8
#define GL 12                 // group-list depth
#define BIGF 1.7014118e38f    // 0x7F000000 — finite sentinel, id bits 0

typedef _Float16 half8 __attribute__((ext_vector_type(8)));
typedef float f32x4 __attribute__((ext_vector_type(4)));
typedef float f32x16 __attribute__((ext_vector_type(16)));

union C16 { f32x16 w; f32x4 q[4]; };

__device__ __forceinline__ float silu(float v) {
    return v / (1.0f + __expf(-v));
}

#define MED3(v, a, b) __builtin_amdgcn_fmed3f((v), (a), (b))

#define INS8V(v) {                      \
    d7 = MED3((v), d6, d7);             \
    d6 = MED3((v), d5, d6);             \
    d5 = MED3((v), d4, d5);             \
    d4 = MED3((v), d3, d4);             \
    d3 = MED3((v), d2, d3);             \
    d2 = MED3((v), d1, d2);             \
    d1 = MED3((v), d0, d1);             \
    d0 = fminf((v), d0); }

// 12-deep sorted-insert (g0..g11)
#define INS12G(v) {                     \
    g11 = MED3((v), g10, g11);          \
    g10 = MED3((v), g9, g10);           \
    g9  = MED3((v), g8, g9);            \
    g8  = MED3((v), g7, g8);            \
    g7  = MED3((v), g6, g7);            \
    g6  = MED3((v), g5, g6);            \
    g5  = MED3((v), g4, g5);            \
    g4  = MED3((v), g3, g4);            \
    g3  = MED3((v), g2, g3);            \
    g2  = MED3((v), g1, g2);            \
    g1  = MED3((v), g0, g1);            \
    g0  = fminf((v), g0); }

#define CSW(p, q) { float lo_ = fminf(m##p, m##q); float hi_ = fmaxf(m##p, m##q); m##p = lo_; m##q = hi_; }

#define CLEAN16() \
    CSW(0,8) CSW(1,9) CSW(2,10) CSW(3,11) CSW(4,12) CSW(5,13) CSW(6,14) CSW(7,15) \
    CSW(0,4) CSW(1,5) CSW(2,6) CSW(3,7) CSW(8,12) CSW(9,13) CSW(10,14) CSW(11,15) \
    CSW(0,2) CSW(1,3) CSW(4,6) CSW(5,7) CSW(8,10) CSW(9,11) CSW(12,14) CSW(13,15) \
    CSW(0,1) CSW(2,3) CSW(4,5) CSW(6,7) CSW(8,9) CSW(10,11) CSW(12,13) CSW(14,15)

#define MERGE12_SHFL(mask) {                                  \
    float b0 = __shfl_xor(g0, (mask), 64);                    \
    float b1 = __shfl_xor(g1, (mask), 64);                    \
    float b2 = __shfl_xor(g2, (mask), 64);                    \
    float b3 = __shfl_xor(g3, (mask), 64);                    \
    float b4 = __shfl_xor(g4, (mask), 64);                    \
    float b5 = __shfl_xor(g5, (mask), 64);                    \
    float b6 = __shfl_xor(g6, (mask), 64);                    \
    float b7 = __shfl_xor(g7, (mask), 64);                    \
    float b8 = __shfl_xor(g8, (mask), 64);                    \
    float b9 = __shfl_xor(g9, (mask), 64);                    \
    float b10 = __shfl_xor(g10, (mask), 64);                  \
    float b11 = __shfl_xor(g11, (mask), 64);                  \
    float m0 = g0, m1 = g1, m2 = g2, m3 = g3;                 \
    float m4 = fminf(g4, b11), m5 = fminf(g5, b10);           \
    float m6 = fminf(g6, b9),  m7 = fminf(g7, b8);            \
    float m8 = fminf(g8, b7),  m9 = fminf(g9, b6);            \
    float m10 = fminf(g10, b5), m11 = fminf(g11, b4);         \
    float m12 = b3, m13 = b2, m14 = b1, m15 = b0;             \
    CLEAN16();                                                \
    g0 = m0; g1 = m1; g2 = m2; g3 = m3; g4 = m4; g5 = m5;     \
    g6 = m6; g7 = m7; g8 = m8; g9 = m9; g10 = m10; g11 = m11; }

#define MERGE12_LDS(LD) {                                     \
    float b0 = LD(0), b1 = LD(1), b2 = LD(2), b3 = LD(3);     \
    float b4 = LD(4), b5 = LD(5), b6 = LD(6), b7 = LD(7);     \
    float b8 = LD(8), b9 = LD(9), b10 = LD(10), b11 = LD(11); \
    float m0 = g0, m1 = g1, m2 = g2, m3 = g3;                 \
    float m4 = fminf(g4, b11), m5 = fminf(g5, b10);           \
    float m6 = fminf(g6, b9),  m7 = fminf(g7, b8);            \
    float m8 = fminf(g8, b7),  m9 = fminf(g9, b6);            \
    float m10 = fminf(g10, b5), m11 = fminf(g11, b4);         \
    float m12 = b3, m13 = b2, m14 = b1, m15 = b0;             \
    CLEAN16();                                                \
    g0 = m0; g1 = m1; g2 = m2; g3 = m3; g4 = m4; g5 = m5;     \
    g6 = m6; g7 = m7; g8 = m8; g9 = m9; g10 = m10; g11 = m11; }

#define MERGE8(mask) {                                   \
    float b0 = __shfl_xor(d0, (mask), 64);               \
    float b1 = __shfl_xor(d1, (mask), 64);               \
    float b2 = __shfl_xor(d2, (mask), 64);               \
    float b3 = __shfl_xor(d3, (mask), 64);               \
    float b4 = __shfl_xor(d4, (mask), 64);               \
    float b5 = __shfl_xor(d5, (mask), 64);               \
    float b6 = __shfl_xor(d6, (mask), 64);               \
    float b7 = __shfl_xor(d7, (mask), 64);               \
    float m0 = fminf(d0, b7), m1 = fminf(d1, b6);        \
    float m2 = fminf(d2, b5), m3 = fminf(d3, b4);        \
    float m4 = fminf(d4, b3), m5 = fminf(d5, b2);        \
    float m6 = fminf(d6, b1), m7 = fminf(d7, b0);        \
    CSW(0,4) CSW(1,5) CSW(2,6) CSW(3,7)                  \
    CSW(0,2) CSW(1,3) CSW(4,6) CSW(5,7)                  \
    CSW(0,1) CSW(2,3) CSW(4,5) CSW(6,7)                  \
    d0 = m0; d1 = m1; d2 = m2; d3 = m3;                  \
    d4 = m4; d5 = m5; d6 = m6; d7 = m7; }

// ---- K1: encoder MLP -> x, H/L/YH/YL f16 splits, SQF, ACC ----
__global__ __launch_bounds__(64) void k_encoder(
    const float* __restrict__ x_pfc,
    const float* __restrict__ W1, const float* __restrict__ b1,
    const float* __restrict__ W2, const float* __restrict__ b2,
    const float* __restrict__ W3, const float* __restrict__ b3,
    const float* __restrict__ We, const float* __restrict__ be,
    float* __restrict__ xo, _Float16* __restrict__ H, _Float16* __restrict__ L,
    _Float16* __restrict__ YH, _Float16* __restrict__ YL,
    float* __restrict__ SQF, float* __restrict__ ACC)
{
    __shared__ float sW1[DIN * 8];
    __shared__ float sb1[8];
    __shared__ float sW2[8 * 16];
    __shared__ float sb2[16];
    __shared__ float sW3[16 * 15];
    __shared__ float sb3[15];
    __shared__ float sWe[16 * 16];
    __shared__ float sbe[16];
    int t = threadIdx.x;
    for (int q = t; q < DIN * 8; q += 64) sW1[q] = W1[q];
    for (int q = t; q < 8; q += 64) sb1[q] = b1[q];
    for (int q = t; q < 8 * 16; q += 64) sW2[q] = W2[q];
    for (int q = t; q < 16; q += 64) sb2[q] = b2[q];
    for (int q = t; q < 16 * 15; q += 64) sW3[q] = W3[q];
    for (int q = t; q < 15; q += 64) sb3[q] = b3[q];
    for (int q = t; q < 16 * 16; q += 64) sWe[q] = We[q];
    for (int q = t; q < 16; q += 64) sbe[q] = be[q];
    __syncthreads();

    int i = blockIdx.x * 64 + t;
    float in[DIN];
#pragma unroll
    for (int d = 0; d < DIN; ++d) in[d] = x_pfc[i * DIN + d];

    float a1[8];
#pragma unroll
    for (int h = 0; h < 8; ++h) a1[h] = sb1[h];
#pragma unroll
    for (int d = 0; d < DIN; ++d) {
        float v = in[d];
#pragma unroll
        for (int h = 0; h < 8; ++h) a1[h] += v * sW1[d * 8 + h];
    }
#pragma unroll
    for (int h = 0; h < 8; ++h) a1[h] = silu(a1[h]);

    float a2[16];
#pragma unroll
    for (int h = 0; h < 16; ++h) a2[h] = sb2[h];
#pragma unroll
    for (int d = 0; d < 8; ++d) {
        float v = a1[d];
#pragma unroll
        for (int h = 0; h < 16; ++h) a2[h] += v * sW2[d * 16 + h];
    }
#pragma unroll
    for (int h = 0; h < 16; ++h) a2[h] = silu(a2[h]);

    float a3[15];
#pragma unroll
    for (int h = 0; h < 15; ++h) a3[h] = sb3[h];
#pragma unroll
    for (int d = 0; d < 16; ++d) {
        float v = a2[d];
#pragma unroll
        for (int h = 0; h < 15; ++h) a3[h] += v * sW3[d * 15 + h];
    }

    float xr[16];
#pragma unroll
    for (int h = 0; h < 15; ++h) xr[h] = a3[h];
    xr[15] = in[DIN - 1];

    float s = 0.0f;
#pragma unroll
    for (int d = 0; d < 16; ++d) s += xr[d] * xr[d];

    float accb[16];
#pragma unroll
    for (int h = 0; h < 16; ++h) accb[h] = sbe[h];
#pragma unroll
    for (int d = 0; d < 16; ++d) {
        float v = xr[d];
#pragma unroll
        for (int h = 0; h < 16; ++h) accb[h] += v * sWe[d * 16 + h];
    }

    _Float16 hb[16], lb[16], yhb[16], ylb[16];
#pragma unroll
    for (int d = 0; d < 16; ++d) {
        _Float16 h = (_Float16)xr[d];
        hb[d] = h;
        lb[d] = (_Float16)(xr[d] - (float)h);
        float y = -2.0f * xr[d];
        _Float16 yh = (_Float16)y;
        yhb[d] = yh;
        ylb[d] = (_Float16)(y - (float)yh);
    }
    {
        uint4* p;
        p = (uint4*)(H + (size_t)i * 16);  p[0] = ((uint4*)hb)[0];  p[1] = ((uint4*)hb)[1];
        p = (uint4*)(L + (size_t)i * 16);  p[0] = ((uint4*)lb)[0];  p[1] = ((uint4*)lb)[1];
        p = (uint4*)(YH + (size_t)i * 16); p[0] = ((uint4*)yhb)[0]; p[1] = ((uint4*)yhb)[1];
        p = (uint4*)(YL + (size_t)i * 16); p[0] = ((uint4*)ylb)[0]; p[1] = ((uint4*)ylb)[1];
        f32x4* xq = (f32x4*)(xo + (size_t)i * 16);
        f32x4* aq = (f32x4*)(ACC + (size_t)i * 16);
#pragma unroll
        for (int q = 0; q < 4; ++q) {
            f32x4 xv, av;
#pragma unroll
            for (int r = 0; r < 4; ++r) { xv[r] = xr[q * 4 + r]; av[r] = accb[q * 4 + r]; }
            xq[q] = xv;
            aq[q] = av;
        }
    }
    SQF[i] = s;
}

// ---- K2: fused knn + head, 32 i-points/block, 16 waves ----
// Round-23: round-22 raised occupancy 20->35% but dur 58->57 — still
// latency-stall bound (pipe demands sum ~25-40us << 57us). This round's
// single variable: TLP 4 -> 8 waves/SIMD. 1024 threads (16 waves), each
// wave sweeps a 1024-j window (32 tiles, same inner-loop shape -> VGPR
// stays ~56; launch_bounds(1024,8) enforces <=64 for 2 blocks/CU).
// id encoding: 10 bits = (global_tile<<1)|hh, tile 0..511;
//   decode jb = (id>>1)*32 + (id&1)*4.
// Merge tree: 16->8->4->2->1 (4 LDS levels). Head: work gated to t<512,
// barriers hoisted so all 16 waves participate.
__global__ __launch_bounds__(1024, 8) void k_knn_head(
    const _Float16* __restrict__ H, const _Float16* __restrict__ L,
    const _Float16* __restrict__ YH, const _Float16* __restrict__ YL,
    const float* __restrict__ SQF, const float* __restrict__ x,
    const float* __restrict__ x_pfc, const float* __restrict__ ACC,
    const float* __restrict__ We,
    const float* __restrict__ Wf1, const float* __restrict__ bf1,
    const float* __restrict__ Wf2, const float* __restrict__ bf2,
    float* __restrict__ out)
{
    __shared__ union SU {
        float knn[16384];                      // 64KB: full sq stage + merge tree
        struct {
            float we2[256]; float wf1[512]; float bf1s[32];
            float wf2[512]; float bf2s[16];
            int cnt[32]; int idx[256];
            float f1[32 * 33];
        } h;
    } S;
    __shared__ unsigned sList[32 * GL];        // survives phase transition (1.5KB)

    int t = threadIdx.x;
    int w = t >> 6;                // 0..15
    int lane = t & 63;
    int r31 = lane & 31;
    int hh = lane >> 5;
    int i0 = blockIdx.x * 32;

    // ================= Phase K: full-j MFMA sweep =================
    {
        int gi = i0 + r31;
        half8 B1 = *(const half8*)(YH + (size_t)gi * 16 + hh * 8);
        half8 B2 = *(const half8*)(YL + (size_t)gi * 16 + hh * 8);

        // stage ALL of SQF (16384 f32 = 4096 f32x4), coalesced
        {
            const f32x4* src = (const f32x4*)SQF;
            f32x4* dst = (f32x4*)S.knn;
            for (int q = t; q < 4096; q += 1024) dst[q] = src[q];
        }

        float g0 = BIGF, g1 = BIGF, g2 = BIGF, g3 = BIGF;
        float g4 = BIGF, g5 = BIGF, g6 = BIGF, g7 = BIGF;
        float g8 = BIGF, g9 = BIGF, g10 = BIGF, g11 = BIGF;

        // wave w sweeps j-window [w*1024, (w+1)*1024): 32 tiles of 32
        const _Float16* pH = H + ((size_t)(w * 1024 + r31)) * 16 + hh * 8;
        const _Float16* pL = L + ((size_t)(w * 1024 + r31)) * 16 + hh * 8;
        const float* sqb = S.knn + w * 1024 + hh * 4;
        unsigned idt = (unsigned)((w << 6) | hh);   // id = (g<<1)|hh, g=w*32+tt

        __syncthreads();   // sq staged

#pragma unroll 2
        for (int tt = 0; tt < 32; ++tt) {
            half8 Ah = *(const half8*)(pH + (size_t)tt * 512);
            half8 Al = *(const half8*)(pL + (size_t)tt * 512);
            const f32x4* s_ = (const f32x4*)(sqb + tt * 32);

            C16 c;
            c.q[0] = s_[0]; c.q[1] = s_[2]; c.q[2] = s_[4]; c.q[3] = s_[6];
            c.w = __builtin_amdgcn_mfma_f32_32x32x16_f16(Ah, B1, c.w, 0, 0, 0);
            c.w = __builtin_amdgcn_mfma_f32_32x32x16_f16(Al, B1, c.w, 0, 0, 0);
            c.w = __builtin_amdgcn_mfma_f32_32x32x16_f16(Ah, B2, c.w, 0, 0, 0);

            float v0 = fminf(fminf(c.w[0], c.w[1]), c.w[2]);
            float v1 = fminf(fminf(c.w[3], c.w[4]), c.w[5]);
            float v2 = fminf(fminf(c.w[6], c.w[7]), c.w[8]);
            float v3 = fminf(fminf(c.w[9], c.w[10]), c.w[11]);
            float v4 = fminf(fminf(c.w[12], c.w[13]), c.w[14]);
            float v5 = fminf(fminf(v0, v1), c.w[15]);
            float v6 = fminf(fminf(v2, v3), v4);
            float vmin = fminf(v5, v6);

            unsigned pk = (__float_as_uint(vmin) & 0xFFFFFC00u)
                        | (idt + (unsigned)(tt << 1));
            float pf = __uint_as_float(pk);
            INS12G(pf);
        }

        MERGE12_SHFL(32);

        __syncthreads();   // sq reads done; S.knn reusable as merge tree

#define STORE12() if (lane < 32) {                           \
            S.knn[(w * GL + 0) * 32 + r31] = g0;             \
            S.knn[(w * GL + 1) * 32 + r31] = g1;             \
            S.knn[(w * GL + 2) * 32 + r31] = g2;             \
            S.knn[(w * GL + 3) * 32 + r31] = g3;             \
            S.knn[(w * GL + 4) * 32 + r31] = g4;             \
            S.knn[(w * GL + 5) * 32 + r31] = g5;             \
            S.knn[(w * GL + 6) * 32 + r31] = g6;             \
            S.knn[(w * GL + 7) * 32 + r31] = g7;             \
            S.knn[(w * GL + 8) * 32 + r31] = g8;             \
            S.knn[(w * GL + 9) * 32 + r31] = g9;             \
            S.knn[(w * GL + 10) * 32 + r31] = g10;           \
            S.knn[(w * GL + 11) * 32 + r31] = g11; }

        if (w >= 8) STORE12();
        __syncthreads();
        if (w < 8) {
            int pw = w + 8;
#define LD(s) S.knn[(pw * GL + (s)) * 32 + r31]
            MERGE12_LDS(LD);
#undef LD
        }
        __syncthreads();
        if (w >= 4 && w < 8) STORE12();
        __syncthreads();
        if (w < 4) {
            int pw = w + 4;
#define LD(s) S.knn[(pw * GL + (s)) * 32 + r31]
            MERGE12_LDS(LD);
#undef LD
        }
        __syncthreads();
        if (w == 2 || w == 3) STORE12();
        __syncthreads();
        if (w < 2) {
            int pw = w + 2;
#define LD(s) S.knn[(pw * GL + (s)) * 32 + r31]
            MERGE12_LDS(LD);
#undef LD
        }
        __syncthreads();
        if (w == 1) STORE12();
        __syncthreads();
        if (w == 0) {
            int pw = 1;
#define LD(s) S.knn[(pw * GL + (s)) * 32 + r31]
            MERGE12_LDS(LD);
#undef LD
            if (lane < 32) {
                // final top-12 lists -> LDS (no CV global round-trip)
                sList[r31 * GL + 0] = __float_as_uint(g0);
                sList[r31 * GL + 1] = __float_as_uint(g1);
                sList[r31 * GL + 2] = __float_as_uint(g2);
                sList[r31 * GL + 3] = __float_as_uint(g3);
                sList[r31 * GL + 4] = __float_as_uint(g4);
                sList[r31 * GL + 5] = __float_as_uint(g5);
                sList[r31 * GL + 6] = __float_as_uint(g6);
                sList[r31 * GL + 7] = __float_as_uint(g7);
                sList[r31 * GL + 8] = __float_as_uint(g8);
                sList[r31 * GL + 9] = __float_as_uint(g9);
                sList[r31 * GL + 10] = __float_as_uint(g10);
                sList[r31 * GL + 11] = __float_as_uint(g11);
            }
        }
#undef STORE12
    }

    __syncthreads();   // lists final; S.knn free for head weights

    // ================= Phase H: head (32 points, 16 lanes each; t<512) ====
    {
        for (int q = t; q < 16 * 16; q += 1024) S.h.we2[q] = We[256 + q];
        for (int q = t; q < 16 * 32; q += 1024) S.h.wf1[q] = Wf1[q];
        for (int q = t; q < 32; q += 1024) S.h.bf1s[q] = bf1[q];
        for (int q = t; q < 32 * 16; q += 1024) S.h.wf2[q] = Wf2[q];
        for (int q = t; q < 16; q += 1024) S.h.bf2s[q] = bf2[q];
        if (t < 32) S.h.cnt[t] = 0;
        __syncthreads();

        int l = t & 15;          // lane within point
        int pt = t >> 4;         // point slot (0..63; only 0..31 active)
        int ql = l & 3;
        int qd = l >> 2;
        int i = i0 + (pt & 31);
        bool act = (t < 512);

        float xi[16];
        float val[12];
        int jbs[12];
        float kth = BIGF;
        f32x4 xiq = {};

        if (act) {
            const f32x4* xiv = (const f32x4*)(x + (size_t)i * 16);
#pragma unroll
            for (int q = 0; q < 4; ++q) {
                f32x4 a = xiv[q];
#pragma unroll
                for (int r = 0; r < 4; ++r) xi[q * 4 + r] = a[r];
            }
            xiq = ((const f32x4*)(x + (size_t)i * 16))[ql];

            // scan A: 12 groups x 4 coalesced runs
            float d0 = BIGF, d1 = BIGF, d2 = BIGF, d3 = BIGF;
            float d4 = BIGF, d5 = BIGF, d6 = BIGF, d7 = BIGF;
#pragma unroll
            for (int g = 0; g < GL; ++g) {
                unsigned id = sList[pt * GL + g] & 0x3FFu;
                int jb = (int)((id >> 1) * 32 + (id & 1) * 4);
                jbs[g] = jb;
                float vg = BIGF;
#pragma unroll
                for (int rho = 0; rho < 4; ++rho) {
                    f32x4 a = *((const f32x4*)(x + ((size_t)(jb + rho * 8)) * 16) + l);
                    float qdot = xiq[0] * a[0];
                    qdot = fmaf(xiq[1], a[1], qdot);
                    qdot = fmaf(xiq[2], a[2], qdot);
                    qdot = fmaf(xiq[3], a[3], qdot);
                    qdot += __shfl_xor(qdot, 1, 64);
                    qdot += __shfl_xor(qdot, 2, 64);
                    float v = fmaf(qdot, -2.0f, SQF[jb + rho * 8 + qd]);
                    vg = (ql == rho) ? v : vg;
                }
                val[g] = vg;
                INS8V(vg);
            }

            // exact kth over the point's 192 candidates (16-lane butterfly)
            MERGE8(1);
            MERGE8(2);
            MERGE8(4);
            MERGE8(8);
            kth = d7;

            // scan B: register re-scan, collect ids
#pragma unroll
            for (int g = 0; g < GL; ++g) {
                float v = val[g];
                if (v <= kth) {
                    int j = jbs[g] + ql * 8 + qd;
                    int p = atomicAdd(&S.h.cnt[pt], 1);
                    if (p < KNN) S.h.idx[pt * 8 + p] = j;
                }
            }
        }
        __syncthreads();

        float p0 = 0.0f, p1 = 0.0f;
        if (act) {
            int e8 = l & 7;
            int j = S.h.idx[pt * 8 + e8];

            float xd[16];
            {
                const f32x4* xjv = (const f32x4*)(x + (size_t)j * 16);
#pragma unroll
                for (int q = 0; q < 4; ++q) {
                    f32x4 a = xjv[q];
#pragma unroll
                    for (int r = 0; r < 4; ++r) xd[q * 4 + r] = a[r] - xi[q * 4 + r];
                }
            }

            float acc[16];
            {
                const f32x4* av = (const f32x4*)(ACC + (size_t)i * 16);
#pragma unroll
                for (int q = 0; q < 4; ++q) {
                    f32x4 a = av[q];
#pragma unroll
                    for (int r = 0; r < 4; ++r) acc[q * 4 + r] = a[r];
                }
            }
#pragma unroll
            for (int d = 0; d < 16; ++d) {
                float v = xd[d];
#pragma unroll
                for (int h = 0; h < 16; ++h) acc[h] += v * S.h.we2[d * 16 + h];
            }

            float feats[16];
#pragma unroll
            for (int h = 0; h < 16; ++h) feats[h] = silu(acc[h]);

#pragma unroll
            for (int mask = 1; mask <= 4; mask <<= 1) {
#pragma unroll
                for (int h = 0; h < 16; ++h) feats[h] += __shfl_xor(feats[h], mask, 64);
            }
#pragma unroll
            for (int h = 0; h < 16; ++h) feats[h] *= 0.125f;

            // f1: lane l computes outputs l and l+16
            p0 = S.h.bf1s[l];
            p1 = S.h.bf1s[l + 16];
#pragma unroll
            for (int k = 0; k < 16; ++k) {
                float v = feats[k];
                p0 = fmaf(v, S.h.wf1[k * 32 + l], p0);
                p1 = fmaf(v, S.h.wf1[k * 32 + l + 16], p1);
            }
            p0 = silu(p0);
            p1 = silu(p1);
            S.h.f1[pt * 33 + l] = p0;
            S.h.f1[pt * 33 + 16 + l] = p1;
        }
        __syncthreads();

        if (act) {
            // f2: lane l computes output l
            float o = S.h.bf2s[l];
#pragma unroll
            for (int k = 0; k < 32; ++k)
                o = fmaf(S.h.f1[pt * 33 + k], S.h.wf2[k * 16 + l], o);

            out[(size_t)i * 29 + l] = o;
            if (l < DIN) out[(size_t)i * 29 + 16 + l] = x_pfc[i * DIN + l];
        }
    }
}

extern "C" void kernel_launch(void* const* d_in, const int* in_sizes, int n_in,
                              void* d_out, int out_size, void* d_ws, size_t ws_size,
                              hipStream_t stream)
{
    const float* x_pfc = (const float*)d_in[0];
    const float* W1 = (const float*)d_in[1];
    const float* b1 = (const float*)d_in[2];
    const float* W2 = (const float*)d_in[3];
    const float* b2 = (const float*)d_in[4];
    const float* W3 = (const float*)d_in[5];
    const float* b3 = (const float*)d_in[6];
    const float* We = (const float*)d_in[7];
    const float* be = (const float*)d_in[8];
    const float* Wf1 = (const float*)d_in[9];
    const float* bf1 = (const float*)d_in[10];
    const float* Wf2 = (const float*)d_in[11];
    const float* bf2 = (const float*)d_in[12];
    float* out = (float*)d_out;

    float* xw = (float*)d_ws;                         // N*16 f32
    float* ACCa = xw + (size_t)NPTS * 16;             // N*16 f32
    _Float16* Ha = (_Float16*)(ACCa + (size_t)NPTS * 16);  // N*16 f16
    _Float16* La = Ha + (size_t)NPTS * 16;
    _Float16* YHa = La + (size_t)NPTS * 16;
    _Float16* YLa = YHa + (size_t)NPTS * 16;
    float* SQFa = (float*)(YLa + (size_t)NPTS * 16);  // N f32

    hipLaunchKernelGGL(k_encoder, dim3(NPTS / 64), dim3(64), 0, stream,
                       x_pfc, W1, b1, W2, b2, W3, b3, We, be,
                       xw, Ha, La, YHa, YLa, SQFa, ACCa);
    hipLaunchKernelGGL(k_knn_head, dim3(NPTS / 32), dim3(1024), 0, stream,
                       Ha, La, YHa, YLa, SQFa, xw, x_pfc, ACCa,
                       We, Wf1, bf1, Wf2, bf2, out);
}

// Round 12
// 142.458 us; speedup vs baseline: 1.0865x; 1.0865x over previous
//
#include <hip/hip_runtime.h>
#include <math.h>

#define NPTS 16384
#define DIN 13
#define KNN 8
#define GL 12                 // group-list depth
#define BIGF 1.7014118e38f    // 0x7F000000 — finite sentinel, id bits 0

typedef _Float16 half8 __attribute__((ext_vector_type(8)));
typedef float f32x4 __attribute__((ext_vector_type(4)));
typedef float f32x16 __attribute__((ext_vector_type(16)));

union C16 { f32x16 w; f32x4 q[4]; };

__device__ __forceinline__ float silu(float v) {
    return v / (1.0f + __expf(-v));
}

#define MED3(v, a, b) __builtin_amdgcn_fmed3f((v), (a), (b))

#define INS8V(v) {                      \
    d7 = MED3((v), d6, d7);             \
    d6 = MED3((v), d5, d6);             \
    d5 = MED3((v), d4, d5);             \
    d4 = MED3((v), d3, d4);             \
    d3 = MED3((v), d2, d3);             \
    d2 = MED3((v), d1, d2);             \
    d1 = MED3((v), d0, d1);             \
    d0 = fminf((v), d0); }

// 12-deep sorted-insert (g0..g11)
#define INS12G(v) {                     \
    g11 = MED3((v), g10, g11);          \
    g10 = MED3((v), g9, g10);           \
    g9  = MED3((v), g8, g9);            \
    g8  = MED3((v), g7, g8);            \
    g7  = MED3((v), g6, g7);            \
    g6  = MED3((v), g5, g6);            \
    g5  = MED3((v), g4, g5);            \
    g4  = MED3((v), g3, g4);            \
    g3  = MED3((v), g2, g3);            \
    g2  = MED3((v), g1, g2);            \
    g1  = MED3((v), g0, g1);            \
    g0  = fminf((v), g0); }

#define CSW(p, q) { float lo_ = fminf(m##p, m##q); float hi_ = fmaxf(m##p, m##q); m##p = lo_; m##q = hi_; }

#define CLEAN16() \
    CSW(0,8) CSW(1,9) CSW(2,10) CSW(3,11) CSW(4,12) CSW(5,13) CSW(6,14) CSW(7,15) \
    CSW(0,4) CSW(1,5) CSW(2,6) CSW(3,7) CSW(8,12) CSW(9,13) CSW(10,14) CSW(11,15) \
    CSW(0,2) CSW(1,3) CSW(4,6) CSW(5,7) CSW(8,10) CSW(9,11) CSW(12,14) CSW(13,15) \
    CSW(0,1) CSW(2,3) CSW(4,5) CSW(6,7) CSW(8,9) CSW(10,11) CSW(12,13) CSW(14,15)

#define MERGE12_SHFL(mask) {                                  \
    float b0 = __shfl_xor(g0, (mask), 64);                    \
    float b1 = __shfl_xor(g1, (mask), 64);                    \
    float b2 = __shfl_xor(g2, (mask), 64);                    \
    float b3 = __shfl_xor(g3, (mask), 64);                    \
    float b4 = __shfl_xor(g4, (mask), 64);                    \
    float b5 = __shfl_xor(g5, (mask), 64);                    \
    float b6 = __shfl_xor(g6, (mask), 64);                    \
    float b7 = __shfl_xor(g7, (mask), 64);                    \
    float b8 = __shfl_xor(g8, (mask), 64);                    \
    float b9 = __shfl_xor(g9, (mask), 64);                    \
    float b10 = __shfl_xor(g10, (mask), 64);                  \
    float b11 = __shfl_xor(g11, (mask), 64);                  \
    float m0 = g0, m1 = g1, m2 = g2, m3 = g3;                 \
    float m4 = fminf(g4, b11), m5 = fminf(g5, b10);           \
    float m6 = fminf(g6, b9),  m7 = fminf(g7, b8);            \
    float m8 = fminf(g8, b7),  m9 = fminf(g9, b6);            \
    float m10 = fminf(g10, b5), m11 = fminf(g11, b4);         \
    float m12 = b3, m13 = b2, m14 = b1, m15 = b0;             \
    CLEAN16();                                                \
    g0 = m0; g1 = m1; g2 = m2; g3 = m3; g4 = m4; g5 = m5;     \
    g6 = m6; g7 = m7; g8 = m8; g9 = m9; g10 = m10; g11 = m11; }

#define MERGE12_LDS(LD) {                                     \
    float b0 = LD(0), b1 = LD(1), b2 = LD(2), b3 = LD(3);     \
    float b4 = LD(4), b5 = LD(5), b6 = LD(6), b7 = LD(7);     \
    float b8 = LD(8), b9 = LD(9), b10 = LD(10), b11 = LD(11); \
    float m0 = g0, m1 = g1, m2 = g2, m3 = g3;                 \
    float m4 = fminf(g4, b11), m5 = fminf(g5, b10);           \
    float m6 = fminf(g6, b9),  m7 = fminf(g7, b8);            \
    float m8 = fminf(g8, b7),  m9 = fminf(g9, b6);            \
    float m10 = fminf(g10, b5), m11 = fminf(g11, b4);         \
    float m12 = b3, m13 = b2, m14 = b1, m15 = b0;             \
    CLEAN16();                                                \
    g0 = m0; g1 = m1; g2 = m2; g3 = m3; g4 = m4; g5 = m5;     \
    g6 = m6; g7 = m7; g8 = m8; g9 = m9; g10 = m10; g11 = m11; }

#define MERGE8(mask) {                                   \
    float b0 = __shfl_xor(d0, (mask), 64);               \
    float b1 = __shfl_xor(d1, (mask), 64);               \
    float b2 = __shfl_xor(d2, (mask), 64);               \
    float b3 = __shfl_xor(d3, (mask), 64);               \
    float b4 = __shfl_xor(d4, (mask), 64);               \
    float b5 = __shfl_xor(d5, (mask), 64);               \
    float b6 = __shfl_xor(d6, (mask), 64);               \
    float b7 = __shfl_xor(d7, (mask), 64);               \
    float m0 = fminf(d0, b7), m1 = fminf(d1, b6);        \
    float m2 = fminf(d2, b5), m3 = fminf(d3, b4);        \
    float m4 = fminf(d4, b3), m5 = fminf(d5, b2);        \
    float m6 = fminf(d6, b1), m7 = fminf(d7, b0);        \
    CSW(0,4) CSW(1,5) CSW(2,6) CSW(3,7)                  \
    CSW(0,2) CSW(1,3) CSW(4,6) CSW(5,7)                  \
    CSW(0,1) CSW(2,3) CSW(4,5) CSW(6,7)                  \
    d0 = m0; d1 = m1; d2 = m2; d3 = m3;                  \
    d4 = m4; d5 = m5; d6 = m6; d7 = m7; }

// ---- K1: encoder MLP -> x, H/L/YH/YL f16 splits, SQF, ACC ----
__global__ __launch_bounds__(64) void k_encoder(
    const float* __restrict__ x_pfc,
    const float* __restrict__ W1, const float* __restrict__ b1,
    const float* __restrict__ W2, const float* __restrict__ b2,
    const float* __restrict__ W3, const float* __restrict__ b3,
    const float* __restrict__ We, const float* __restrict__ be,
    float* __restrict__ xo, _Float16* __restrict__ H, _Float16* __restrict__ L,
    _Float16* __restrict__ YH, _Float16* __restrict__ YL,
    float* __restrict__ SQF, float* __restrict__ ACC)
{
    __shared__ float sW1[DIN * 8];
    __shared__ float sb1[8];
    __shared__ float sW2[8 * 16];
    __shared__ float sb2[16];
    __shared__ float sW3[16 * 15];
    __shared__ float sb3[15];
    __shared__ float sWe[16 * 16];
    __shared__ float sbe[16];
    int t = threadIdx.x;
    for (int q = t; q < DIN * 8; q += 64) sW1[q] = W1[q];
    for (int q = t; q < 8; q += 64) sb1[q] = b1[q];
    for (int q = t; q < 8 * 16; q += 64) sW2[q] = W2[q];
    for (int q = t; q < 16; q += 64) sb2[q] = b2[q];
    for (int q = t; q < 16 * 15; q += 64) sW3[q] = W3[q];
    for (int q = t; q < 15; q += 64) sb3[q] = b3[q];
    for (int q = t; q < 16 * 16; q += 64) sWe[q] = We[q];
    for (int q = t; q < 16; q += 64) sbe[q] = be[q];
    __syncthreads();

    int i = blockIdx.x * 64 + t;
    float in[DIN];
#pragma unroll
    for (int d = 0; d < DIN; ++d) in[d] = x_pfc[i * DIN + d];

    float a1[8];
#pragma unroll
    for (int h = 0; h < 8; ++h) a1[h] = sb1[h];
#pragma unroll
    for (int d = 0; d < DIN; ++d) {
        float v = in[d];
#pragma unroll
        for (int h = 0; h < 8; ++h) a1[h] += v * sW1[d * 8 + h];
    }
#pragma unroll
    for (int h = 0; h < 8; ++h) a1[h] = silu(a1[h]);

    float a2[16];
#pragma unroll
    for (int h = 0; h < 16; ++h) a2[h] = sb2[h];
#pragma unroll
    for (int d = 0; d < 8; ++d) {
        float v = a1[d];
#pragma unroll
        for (int h = 0; h < 16; ++h) a2[h] += v * sW2[d * 16 + h];
    }
#pragma unroll
    for (int h = 0; h < 16; ++h) a2[h] = silu(a2[h]);

    float a3[15];
#pragma unroll
    for (int h = 0; h < 15; ++h) a3[h] = sb3[h];
#pragma unroll
    for (int d = 0; d < 16; ++d) {
        float v = a2[d];
#pragma unroll
        for (int h = 0; h < 15; ++h) a3[h] += v * sW3[d * 15 + h];
    }

    float xr[16];
#pragma unroll
    for (int h = 0; h < 15; ++h) xr[h] = a3[h];
    xr[15] = in[DIN - 1];

    float s = 0.0f;
#pragma unroll
    for (int d = 0; d < 16; ++d) s += xr[d] * xr[d];

    float accb[16];
#pragma unroll
    for (int h = 0; h < 16; ++h) accb[h] = sbe[h];
#pragma unroll
    for (int d = 0; d < 16; ++d) {
        float v = xr[d];
#pragma unroll
        for (int h = 0; h < 16; ++h) accb[h] += v * sWe[d * 16 + h];
    }

    _Float16 hb[16], lb[16], yhb[16], ylb[16];
#pragma unroll
    for (int d = 0; d < 16; ++d) {
        _Float16 h = (_Float16)xr[d];
        hb[d] = h;
        lb[d] = (_Float16)(xr[d] - (float)h);
        float y = -2.0f * xr[d];
        _Float16 yh = (_Float16)y;
        yhb[d] = yh;
        ylb[d] = (_Float16)(y - (float)yh);
    }
    {
        uint4* p;
        p = (uint4*)(H + (size_t)i * 16);  p[0] = ((uint4*)hb)[0];  p[1] = ((uint4*)hb)[1];
        p = (uint4*)(L + (size_t)i * 16);  p[0] = ((uint4*)lb)[0];  p[1] = ((uint4*)lb)[1];
        p = (uint4*)(YH + (size_t)i * 16); p[0] = ((uint4*)yhb)[0]; p[1] = ((uint4*)yhb)[1];
        p = (uint4*)(YL + (size_t)i * 16); p[0] = ((uint4*)ylb)[0]; p[1] = ((uint4*)ylb)[1];
        f32x4* xq = (f32x4*)(xo + (size_t)i * 16);
        f32x4* aq = (f32x4*)(ACC + (size_t)i * 16);
#pragma unroll
        for (int q = 0; q < 4; ++q) {
            f32x4 xv, av;
#pragma unroll
            for (int r = 0; r < 4; ++r) { xv[r] = xr[q * 4 + r]; av[r] = accb[q * 4 + r]; }
            xq[q] = xv;
            aq[q] = av;
        }
    }
    SQF[i] = s;
}

// ---- K2: fused knn + head, 32 i-points/block, 16 waves ----
// Round-24: round-23 (1024 thr, 8 waves/SIMD) hit 74% occupancy but
// SPILLED (VGPR capped 32, WRITE 15MB scratch) -> 75us. Head's
// xi[16]+val[12]+jbs[12]+d[8] (~70 regs) didn't fit the 64-reg cap.
// Register diet (knn phase unchanged, fits):
//  - no xi[16]: keep only xiq; tail reloads x[i]/x[j] quad-by-quad
//    (L2-hot, short-lived)
//  - no jbs[12]: scan B re-decodes ids from sList (2 VALU each)
// Peak head liveness ~40 regs -> spill-free at (1024,8).
__global__ __launch_bounds__(1024, 8) void k_knn_head(
    const _Float16* __restrict__ H, const _Float16* __restrict__ L,
    const _Float16* __restrict__ YH, const _Float16* __restrict__ YL,
    const float* __restrict__ SQF, const float* __restrict__ x,
    const float* __restrict__ x_pfc, const float* __restrict__ ACC,
    const float* __restrict__ We,
    const float* __restrict__ Wf1, const float* __restrict__ bf1,
    const float* __restrict__ Wf2, const float* __restrict__ bf2,
    float* __restrict__ out)
{
    __shared__ union SU {
        float knn[16384];                      // 64KB: full sq stage + merge tree
        struct {
            float we2[256]; float wf1[512]; float bf1s[32];
            float wf2[512]; float bf2s[16];
            int cnt[32]; int idx[256];
            float f1[32 * 33];
        } h;
    } S;
    __shared__ unsigned sList[32 * GL];        // survives phase transition (1.5KB)

    int t = threadIdx.x;
    int w = t >> 6;                // 0..15
    int lane = t & 63;
    int r31 = lane & 31;
    int hh = lane >> 5;
    int i0 = blockIdx.x * 32;

    // ================= Phase K: full-j MFMA sweep =================
    {
        int gi = i0 + r31;
        half8 B1 = *(const half8*)(YH + (size_t)gi * 16 + hh * 8);
        half8 B2 = *(const half8*)(YL + (size_t)gi * 16 + hh * 8);

        // stage ALL of SQF (16384 f32 = 4096 f32x4), coalesced
        {
            const f32x4* src = (const f32x4*)SQF;
            f32x4* dst = (f32x4*)S.knn;
            for (int q = t; q < 4096; q += 1024) dst[q] = src[q];
        }

        float g0 = BIGF, g1 = BIGF, g2 = BIGF, g3 = BIGF;
        float g4 = BIGF, g5 = BIGF, g6 = BIGF, g7 = BIGF;
        float g8 = BIGF, g9 = BIGF, g10 = BIGF, g11 = BIGF;

        // wave w sweeps j-window [w*1024, (w+1)*1024): 32 tiles of 32
        const _Float16* pH = H + ((size_t)(w * 1024 + r31)) * 16 + hh * 8;
        const _Float16* pL = L + ((size_t)(w * 1024 + r31)) * 16 + hh * 8;
        const float* sqb = S.knn + w * 1024 + hh * 4;
        unsigned idt = (unsigned)((w << 6) | hh);   // id = (g<<1)|hh, g=w*32+tt

        __syncthreads();   // sq staged

#pragma unroll 2
        for (int tt = 0; tt < 32; ++tt) {
            half8 Ah = *(const half8*)(pH + (size_t)tt * 512);
            half8 Al = *(const half8*)(pL + (size_t)tt * 512);
            const f32x4* s_ = (const f32x4*)(sqb + tt * 32);

            C16 c;
            c.q[0] = s_[0]; c.q[1] = s_[2]; c.q[2] = s_[4]; c.q[3] = s_[6];
            c.w = __builtin_amdgcn_mfma_f32_32x32x16_f16(Ah, B1, c.w, 0, 0, 0);
            c.w = __builtin_amdgcn_mfma_f32_32x32x16_f16(Al, B1, c.w, 0, 0, 0);
            c.w = __builtin_amdgcn_mfma_f32_32x32x16_f16(Ah, B2, c.w, 0, 0, 0);

            float v0 = fminf(fminf(c.w[0], c.w[1]), c.w[2]);
            float v1 = fminf(fminf(c.w[3], c.w[4]), c.w[5]);
            float v2 = fminf(fminf(c.w[6], c.w[7]), c.w[8]);
            float v3 = fminf(fminf(c.w[9], c.w[10]), c.w[11]);
            float v4 = fminf(fminf(c.w[12], c.w[13]), c.w[14]);
            float v5 = fminf(fminf(v0, v1), c.w[15]);
            float v6 = fminf(fminf(v2, v3), v4);
            float vmin = fminf(v5, v6);

            unsigned pk = (__float_as_uint(vmin) & 0xFFFFFC00u)
                        | (idt + (unsigned)(tt << 1));
            float pf = __uint_as_float(pk);
            INS12G(pf);
        }

        MERGE12_SHFL(32);

        __syncthreads();   // sq reads done; S.knn reusable as merge tree

#define STORE12() if (lane < 32) {                           \
            S.knn[(w * GL + 0) * 32 + r31] = g0;             \
            S.knn[(w * GL + 1) * 32 + r31] = g1;             \
            S.knn[(w * GL + 2) * 32 + r31] = g2;             \
            S.knn[(w * GL + 3) * 32 + r31] = g3;             \
            S.knn[(w * GL + 4) * 32 + r31] = g4;             \
            S.knn[(w * GL + 5) * 32 + r31] = g5;             \
            S.knn[(w * GL + 6) * 32 + r31] = g6;             \
            S.knn[(w * GL + 7) * 32 + r31] = g7;             \
            S.knn[(w * GL + 8) * 32 + r31] = g8;             \
            S.knn[(w * GL + 9) * 32 + r31] = g9;             \
            S.knn[(w * GL + 10) * 32 + r31] = g10;           \
            S.knn[(w * GL + 11) * 32 + r31] = g11; }

        if (w >= 8) STORE12();
        __syncthreads();
        if (w < 8) {
            int pw = w + 8;
#define LD(s) S.knn[(pw * GL + (s)) * 32 + r31]
            MERGE12_LDS(LD);
#undef LD
        }
        __syncthreads();
        if (w >= 4 && w < 8) STORE12();
        __syncthreads();
        if (w < 4) {
            int pw = w + 4;
#define LD(s) S.knn[(pw * GL + (s)) * 32 + r31]
            MERGE12_LDS(LD);
#undef LD
        }
        __syncthreads();
        if (w == 2 || w == 3) STORE12();
        __syncthreads();
        if (w < 2) {
            int pw = w + 2;
#define LD(s) S.knn[(pw * GL + (s)) * 32 + r31]
            MERGE12_LDS(LD);
#undef LD
        }
        __syncthreads();
        if (w == 1) STORE12();
        __syncthreads();
        if (w == 0) {
            int pw = 1;
#define LD(s) S.knn[(pw * GL + (s)) * 32 + r31]
            MERGE12_LDS(LD);
#undef LD
            if (lane < 32) {
                // final top-12 lists -> LDS (no CV global round-trip)
                sList[r31 * GL + 0] = __float_as_uint(g0);
                sList[r31 * GL + 1] = __float_as_uint(g1);
                sList[r31 * GL + 2] = __float_as_uint(g2);
                sList[r31 * GL + 3] = __float_as_uint(g3);
                sList[r31 * GL + 4] = __float_as_uint(g4);
                sList[r31 * GL + 5] = __float_as_uint(g5);
                sList[r31 * GL + 6] = __float_as_uint(g6);
                sList[r31 * GL + 7] = __float_as_uint(g7);
                sList[r31 * GL + 8] = __float_as_uint(g8);
                sList[r31 * GL + 9] = __float_as_uint(g9);
                sList[r31 * GL + 10] = __float_as_uint(g10);
                sList[r31 * GL + 11] = __float_as_uint(g11);
            }
        }
#undef STORE12
    }

    __syncthreads();   // lists final; S.knn free for head weights

    // ========== Phase H: head (32 points, 16 lanes each; t<512) ==========
    {
        for (int q = t; q < 16 * 16; q += 1024) S.h.we2[q] = We[256 + q];
        for (int q = t; q < 16 * 32; q += 1024) S.h.wf1[q] = Wf1[q];
        for (int q = t; q < 32; q += 1024) S.h.bf1s[q] = bf1[q];
        for (int q = t; q < 32 * 16; q += 1024) S.h.wf2[q] = Wf2[q];
        for (int q = t; q < 16; q += 1024) S.h.bf2s[q] = bf2[q];
        if (t < 32) S.h.cnt[t] = 0;
        __syncthreads();

        int l = t & 15;          // lane within point
        int pt = t >> 4;         // point slot (0..63; only 0..31 active)
        int ql = l & 3;
        int qd = l >> 2;
        int i = i0 + (pt & 31);
        bool act = (t < 512);

        float val[12];
        float kth = BIGF;

        if (act) {
            f32x4 xiq = ((const f32x4*)(x + (size_t)i * 16))[ql];

            // scan A: 12 groups x 4 coalesced runs (no jbs[], no xi[])
            float d0 = BIGF, d1 = BIGF, d2 = BIGF, d3 = BIGF;
            float d4 = BIGF, d5 = BIGF, d6 = BIGF, d7 = BIGF;
#pragma unroll
            for (int g = 0; g < GL; ++g) {
                unsigned id = sList[pt * GL + g] & 0x3FFu;
                int jb = (int)((id >> 1) * 32 + (id & 1) * 4);
                float vg = BIGF;
#pragma unroll
                for (int rho = 0; rho < 4; ++rho) {
                    f32x4 a = *((const f32x4*)(x + ((size_t)(jb + rho * 8)) * 16) + l);
                    float qdot = xiq[0] * a[0];
                    qdot = fmaf(xiq[1], a[1], qdot);
                    qdot = fmaf(xiq[2], a[2], qdot);
                    qdot = fmaf(xiq[3], a[3], qdot);
                    qdot += __shfl_xor(qdot, 1, 64);
                    qdot += __shfl_xor(qdot, 2, 64);
                    float v = fmaf(qdot, -2.0f, SQF[jb + rho * 8 + qd]);
                    vg = (ql == rho) ? v : vg;
                }
                val[g] = vg;
                INS8V(vg);
            }

            // exact kth over the point's 192 candidates (16-lane butterfly)
            MERGE8(1);
            MERGE8(2);
            MERGE8(4);
            MERGE8(8);
            kth = d7;

            // scan B: register re-scan, re-decode ids from sList
#pragma unroll
            for (int g = 0; g < GL; ++g) {
                float v = val[g];
                if (v <= kth) {
                    unsigned id = sList[pt * GL + g] & 0x3FFu;
                    int j = (int)((id >> 1) * 32 + (id & 1) * 4) + ql * 8 + qd;
                    int p = atomicAdd(&S.h.cnt[pt], 1);
                    if (p < KNN) S.h.idx[pt * 8 + p] = j;
                }
            }
        }
        __syncthreads();

        if (act) {
            int e8 = l & 7;
            int j = S.h.idx[pt * 8 + e8];

            // acc = ACC[i] + (x[j]-x[i]) @ We2  — reload x quads, short-lived
            float acc[16];
            {
                const f32x4* av = (const f32x4*)(ACC + (size_t)i * 16);
#pragma unroll
                for (int q = 0; q < 4; ++q) {
                    f32x4 a = av[q];
#pragma unroll
                    for (int r = 0; r < 4; ++r) acc[q * 4 + r] = a[r];
                }
            }
            {
                const f32x4* xjv = (const f32x4*)(x + (size_t)j * 16);
                const f32x4* xiv = (const f32x4*)(x + (size_t)i * 16);
#pragma unroll
                for (int q = 0; q < 4; ++q) {
                    f32x4 aj = xjv[q];
                    f32x4 ai = xiv[q];
#pragma unroll
                    for (int r = 0; r < 4; ++r) {
                        float v = aj[r] - ai[r];
                        int d = q * 4 + r;
#pragma unroll
                        for (int h = 0; h < 16; ++h)
                            acc[h] += v * S.h.we2[d * 16 + h];
                    }
                }
            }

            float feats[16];
#pragma unroll
            for (int h = 0; h < 16; ++h) feats[h] = silu(acc[h]);

#pragma unroll
            for (int mask = 1; mask <= 4; mask <<= 1) {
#pragma unroll
                for (int h = 0; h < 16; ++h) feats[h] += __shfl_xor(feats[h], mask, 64);
            }
#pragma unroll
            for (int h = 0; h < 16; ++h) feats[h] *= 0.125f;

            // f1: lane l computes outputs l and l+16
            float p0 = S.h.bf1s[l];
            float p1 = S.h.bf1s[l + 16];
#pragma unroll
            for (int k = 0; k < 16; ++k) {
                float v = feats[k];
                p0 = fmaf(v, S.h.wf1[k * 32 + l], p0);
                p1 = fmaf(v, S.h.wf1[k * 32 + l + 16], p1);
            }
            p0 = silu(p0);
            p1 = silu(p1);
            S.h.f1[pt * 33 + l] = p0;
            S.h.f1[pt * 33 + 16 + l] = p1;
        }
        __syncthreads();

        if (act) {
            // f2: lane l computes output l
            float o = S.h.bf2s[l];
#pragma unroll
            for (int k = 0; k < 32; ++k)
                o = fmaf(S.h.f1[pt * 33 + k], S.h.wf2[k * 16 + l], o);

            out[(size_t)i * 29 + l] = o;
            if (l < DIN) out[(size_t)i * 29 + 16 + l] = x_pfc[i * DIN + l];
        }
    }
}

extern "C" void kernel_launch(void* const* d_in, const int* in_sizes, int n_in,
                              void* d_out, int out_size, void* d_ws, size_t ws_size,
                              hipStream_t stream)
{
    const float* x_pfc = (const float*)d_in[0];
    const float* W1 = (const float*)d_in[1];
    const float* b1 = (const float*)d_in[2];
    const float* W2 = (const float*)d_in[3];
    const float* b2 = (const float*)d_in[4];
    const float* W3 = (const float*)d_in[5];
    const float* b3 = (const float*)d_in[6];
    const float* We = (const float*)d_in[7];
    const float* be = (const float*)d_in[8];
    const float* Wf1 = (const float*)d_in[9];
    const float* bf1 = (const float*)d_in[10];
    const float* Wf2 = (const float*)d_in[11];
    const float* bf2 = (const float*)d_in[12];
    float* out = (float*)d_out;

    float* xw = (float*)d_ws;                         // N*16 f32
    float* ACCa = xw + (size_t)NPTS * 16;             // N*16 f32
    _Float16* Ha = (_Float16*)(ACCa + (size_t)NPTS * 16);  // N*16 f16
    _Float16* La = Ha + (size_t)NPTS * 16;
    _Float16* YHa = La + (size_t)NPTS * 16;
    _Float16* YLa = YHa + (size_t)NPTS * 16;
    float* SQFa = (float*)(YLa + (size_t)NPTS * 16);  // N f32

    hipLaunchKernelGGL(k_encoder, dim3(NPTS / 64), dim3(64), 0, stream,
                       x_pfc, W1, b1, W2, b2, W3, b3, We, be,
                       xw, Ha, La, YHa, YLa, SQFa, ACCa);
    hipLaunchKernelGGL(k_knn_head, dim3(NPTS / 32), dim3(1024), 0, stream,
                       Ha, La, YHa, YLa, SQFa, xw, x_pfc, ACCa,
                       We, Wf1, bf1, Wf2, bf2, out);
}

// Round 13
// 135.913 us; speedup vs baseline: 1.1388x; 1.0482x over previous
//
#include <hip/hip_runtime.h>
#include <math.h>

#define NPTS 16384
#define DIN 13
#define KNN 8
#define GL 12                 // group-list depth
#define BIGF 1.7014118e38f    // 0x7F000000 — finite sentinel, id bits 0

typedef _Float16 half8 __attribute__((ext_vector_type(8)));
typedef float f32x4 __attribute__((ext_vector_type(4)));
typedef float f32x16 __attribute__((ext_vector_type(16)));

union C16 { f32x16 w; f32x4 q[4]; };

__device__ __forceinline__ float silu(float v) {
    return v / (1.0f + __expf(-v));
}

#define MED3(v, a, b) __builtin_amdgcn_fmed3f((v), (a), (b))

#define INS8V(v) {                      \
    d7 = MED3((v), d6, d7);             \
    d6 = MED3((v), d5, d6);             \
    d5 = MED3((v), d4, d5);             \
    d4 = MED3((v), d3, d4);             \
    d3 = MED3((v), d2, d3);             \
    d2 = MED3((v), d1, d2);             \
    d1 = MED3((v), d0, d1);             \
    d0 = fminf((v), d0); }

// 12-deep sorted-insert (g0..g11)
#define INS12G(v) {                     \
    g11 = MED3((v), g10, g11);          \
    g10 = MED3((v), g9, g10);           \
    g9  = MED3((v), g8, g9);            \
    g8  = MED3((v), g7, g8);            \
    g7  = MED3((v), g6, g7);            \
    g6  = MED3((v), g5, g6);            \
    g5  = MED3((v), g4, g5);            \
    g4  = MED3((v), g3, g4);            \
    g3  = MED3((v), g2, g3);            \
    g2  = MED3((v), g1, g2);            \
    g1  = MED3((v), g0, g1);            \
    g0  = fminf((v), g0); }

#define CSW(p, q) { float lo_ = fminf(m##p, m##q); float hi_ = fmaxf(m##p, m##q); m##p = lo_; m##q = hi_; }

#define CLEAN16() \
    CSW(0,8) CSW(1,9) CSW(2,10) CSW(3,11) CSW(4,12) CSW(5,13) CSW(6,14) CSW(7,15) \
    CSW(0,4) CSW(1,5) CSW(2,6) CSW(3,7) CSW(8,12) CSW(9,13) CSW(10,14) CSW(11,15) \
    CSW(0,2) CSW(1,3) CSW(4,6) CSW(5,7) CSW(8,10) CSW(9,11) CSW(12,14) CSW(13,15) \
    CSW(0,1) CSW(2,3) CSW(4,5) CSW(6,7) CSW(8,9) CSW(10,11) CSW(12,13) CSW(14,15)

#define MERGE12_SHFL(mask) {                                  \
    float b0 = __shfl_xor(g0, (mask), 64);                    \
    float b1 = __shfl_xor(g1, (mask), 64);                    \
    float b2 = __shfl_xor(g2, (mask), 64);                    \
    float b3 = __shfl_xor(g3, (mask), 64);                    \
    float b4 = __shfl_xor(g4, (mask), 64);                    \
    float b5 = __shfl_xor(g5, (mask), 64);                    \
    float b6 = __shfl_xor(g6, (mask), 64);                    \
    float b7 = __shfl_xor(g7, (mask), 64);                    \
    float b8 = __shfl_xor(g8, (mask), 64);                    \
    float b9 = __shfl_xor(g9, (mask), 64);                    \
    float b10 = __shfl_xor(g10, (mask), 64);                  \
    float b11 = __shfl_xor(g11, (mask), 64);                  \
    float m0 = g0, m1 = g1, m2 = g2, m3 = g3;                 \
    float m4 = fminf(g4, b11), m5 = fminf(g5, b10);           \
    float m6 = fminf(g6, b9),  m7 = fminf(g7, b8);            \
    float m8 = fminf(g8, b7),  m9 = fminf(g9, b6);            \
    float m10 = fminf(g10, b5), m11 = fminf(g11, b4);         \
    float m12 = b3, m13 = b2, m14 = b1, m15 = b0;             \
    CLEAN16();                                                \
    g0 = m0; g1 = m1; g2 = m2; g3 = m3; g4 = m4; g5 = m5;     \
    g6 = m6; g7 = m7; g8 = m8; g9 = m9; g10 = m10; g11 = m11; }

#define MERGE12_LDS(LD) {                                     \
    float b0 = LD(0), b1 = LD(1), b2 = LD(2), b3 = LD(3);     \
    float b4 = LD(4), b5 = LD(5), b6 = LD(6), b7 = LD(7);     \
    float b8 = LD(8), b9 = LD(9), b10 = LD(10), b11 = LD(11); \
    float m0 = g0, m1 = g1, m2 = g2, m3 = g3;                 \
    float m4 = fminf(g4, b11), m5 = fminf(g5, b10);           \
    float m6 = fminf(g6, b9),  m7 = fminf(g7, b8);            \
    float m8 = fminf(g8, b7),  m9 = fminf(g9, b6);            \
    float m10 = fminf(g10, b5), m11 = fminf(g11, b4);         \
    float m12 = b3, m13 = b2, m14 = b1, m15 = b0;             \
    CLEAN16();                                                \
    g0 = m0; g1 = m1; g2 = m2; g3 = m3; g4 = m4; g5 = m5;     \
    g6 = m6; g7 = m7; g8 = m8; g9 = m9; g10 = m10; g11 = m11; }

#define MERGE8(mask) {                                   \
    float b0 = __shfl_xor(d0, (mask), 64);               \
    float b1 = __shfl_xor(d1, (mask), 64);               \
    float b2 = __shfl_xor(d2, (mask), 64);               \
    float b3 = __shfl_xor(d3, (mask), 64);               \
    float b4 = __shfl_xor(d4, (mask), 64);               \
    float b5 = __shfl_xor(d5, (mask), 64);               \
    float b6 = __shfl_xor(d6, (mask), 64);               \
    float b7 = __shfl_xor(d7, (mask), 64);               \
    float m0 = fminf(d0, b7), m1 = fminf(d1, b6);        \
    float m2 = fminf(d2, b5), m3 = fminf(d3, b4);        \
    float m4 = fminf(d4, b3), m5 = fminf(d5, b2);        \
    float m6 = fminf(d6, b1), m7 = fminf(d7, b0);        \
    CSW(0,4) CSW(1,5) CSW(2,6) CSW(3,7)                  \
    CSW(0,2) CSW(1,3) CSW(4,6) CSW(5,7)                  \
    CSW(0,1) CSW(2,3) CSW(4,5) CSW(6,7)                  \
    d0 = m0; d1 = m1; d2 = m2; d3 = m3;                  \
    d4 = m4; d5 = m5; d6 = m6; d7 = m7; }

// ---- K1: encoder MLP -> x, H/L/YH f16 splits, SQF, ACC ----
// Round-25: YL removed (knn now uses 2 MFMAs; y-lo correction dropped —
// head re-ranks 192 candidates exactly in f32, so ~4e-4 group-min error
// is tolerable).
__global__ __launch_bounds__(64) void k_encoder(
    const float* __restrict__ x_pfc,
    const float* __restrict__ W1, const float* __restrict__ b1,
    const float* __restrict__ W2, const float* __restrict__ b2,
    const float* __restrict__ W3, const float* __restrict__ b3,
    const float* __restrict__ We, const float* __restrict__ be,
    float* __restrict__ xo, _Float16* __restrict__ H, _Float16* __restrict__ L,
    _Float16* __restrict__ YH,
    float* __restrict__ SQF, float* __restrict__ ACC)
{
    __shared__ float sW1[DIN * 8];
    __shared__ float sb1[8];
    __shared__ float sW2[8 * 16];
    __shared__ float sb2[16];
    __shared__ float sW3[16 * 15];
    __shared__ float sb3[15];
    __shared__ float sWe[16 * 16];
    __shared__ float sbe[16];
    int t = threadIdx.x;
    for (int q = t; q < DIN * 8; q += 64) sW1[q] = W1[q];
    for (int q = t; q < 8; q += 64) sb1[q] = b1[q];
    for (int q = t; q < 8 * 16; q += 64) sW2[q] = W2[q];
    for (int q = t; q < 16; q += 64) sb2[q] = b2[q];
    for (int q = t; q < 16 * 15; q += 64) sW3[q] = W3[q];
    for (int q = t; q < 15; q += 64) sb3[q] = b3[q];
    for (int q = t; q < 16 * 16; q += 64) sWe[q] = We[q];
    for (int q = t; q < 16; q += 64) sbe[q] = be[q];
    __syncthreads();

    int i = blockIdx.x * 64 + t;
    float in[DIN];
#pragma unroll
    for (int d = 0; d < DIN; ++d) in[d] = x_pfc[i * DIN + d];

    float a1[8];
#pragma unroll
    for (int h = 0; h < 8; ++h) a1[h] = sb1[h];
#pragma unroll
    for (int d = 0; d < DIN; ++d) {
        float v = in[d];
#pragma unroll
        for (int h = 0; h < 8; ++h) a1[h] += v * sW1[d * 8 + h];
    }
#pragma unroll
    for (int h = 0; h < 8; ++h) a1[h] = silu(a1[h]);

    float a2[16];
#pragma unroll
    for (int h = 0; h < 16; ++h) a2[h] = sb2[h];
#pragma unroll
    for (int d = 0; d < 8; ++d) {
        float v = a1[d];
#pragma unroll
        for (int h = 0; h < 16; ++h) a2[h] += v * sW2[d * 16 + h];
    }
#pragma unroll
    for (int h = 0; h < 16; ++h) a2[h] = silu(a2[h]);

    float a3[15];
#pragma unroll
    for (int h = 0; h < 15; ++h) a3[h] = sb3[h];
#pragma unroll
    for (int d = 0; d < 16; ++d) {
        float v = a2[d];
#pragma unroll
        for (int h = 0; h < 15; ++h) a3[h] += v * sW3[d * 15 + h];
    }

    float xr[16];
#pragma unroll
    for (int h = 0; h < 15; ++h) xr[h] = a3[h];
    xr[15] = in[DIN - 1];

    float s = 0.0f;
#pragma unroll
    for (int d = 0; d < 16; ++d) s += xr[d] * xr[d];

    float accb[16];
#pragma unroll
    for (int h = 0; h < 16; ++h) accb[h] = sbe[h];
#pragma unroll
    for (int d = 0; d < 16; ++d) {
        float v = xr[d];
#pragma unroll
        for (int h = 0; h < 16; ++h) accb[h] += v * sWe[d * 16 + h];
    }

    _Float16 hb[16], lb[16], yhb[16];
#pragma unroll
    for (int d = 0; d < 16; ++d) {
        _Float16 h = (_Float16)xr[d];
        hb[d] = h;
        lb[d] = (_Float16)(xr[d] - (float)h);
        yhb[d] = (_Float16)(-2.0f * xr[d]);
    }
    {
        uint4* p;
        p = (uint4*)(H + (size_t)i * 16);  p[0] = ((uint4*)hb)[0];  p[1] = ((uint4*)hb)[1];
        p = (uint4*)(L + (size_t)i * 16);  p[0] = ((uint4*)lb)[0];  p[1] = ((uint4*)lb)[1];
        p = (uint4*)(YH + (size_t)i * 16); p[0] = ((uint4*)yhb)[0]; p[1] = ((uint4*)yhb)[1];
        f32x4* xq = (f32x4*)(xo + (size_t)i * 16);
        f32x4* aq = (f32x4*)(ACC + (size_t)i * 16);
#pragma unroll
        for (int q = 0; q < 4; ++q) {
            f32x4 xv, av;
#pragma unroll
            for (int r = 0; r < 4; ++r) { xv[r] = xr[q * 4 + r]; av[r] = accb[q * 4 + r]; }
            xq[q] = xv;
            aq[q] = av;
        }
    }
    SQF[i] = s;
}

// ---- K2: fused knn + head, 32 i-points/block, full-j sweep ----
// Round-25: revert to the round-10 shape (best total 136.97; the round-23/24
// TLP experiment proved occupancy is NOT the lever: 35%->70% occ left dur
// flat). Single change vs round 10: 2 MFMAs/tile instead of 3.
//   C = sq + Ah.B1 + Al.B1 = sq - 2 x . f16(2 x_j)   (exact in x)
// Cuts the largest per-SIMD demand stream (matrix pipe ~20.6us -> ~13.7us)
// and shortens the serial MFMA chain. Error ~4e-4 on group-mins; head
// re-ranks 192 candidates exactly in f32, so selection is robust.
__global__ __launch_bounds__(512, 4) void k_knn_head(
    const _Float16* __restrict__ H, const _Float16* __restrict__ L,
    const _Float16* __restrict__ YH,
    const float* __restrict__ SQF, const float* __restrict__ x,
    const float* __restrict__ x_pfc, const float* __restrict__ ACC,
    const float* __restrict__ We,
    const float* __restrict__ Wf1, const float* __restrict__ bf1,
    const float* __restrict__ Wf2, const float* __restrict__ bf2,
    float* __restrict__ out)
{
    __shared__ union SU {
        float knn[16384];                      // 64KB: full sq stage + merge tree
        struct {
            float we2[256]; float wf1[512]; float bf1s[32];
            float wf2[512]; float bf2s[16];
            int cnt[32]; int idx[256];
            float f1[32 * 33];
        } h;
    } S;
    __shared__ unsigned sList[32 * GL];        // survives phase transition (1.5KB)

    int t = threadIdx.x;
    int w = t >> 6;
    int lane = t & 63;
    int r31 = lane & 31;
    int hh = lane >> 5;
    int i0 = blockIdx.x * 32;

    // ================= Phase K: full-j MFMA sweep =================
    {
        int gi = i0 + r31;
        half8 B1 = *(const half8*)(YH + (size_t)gi * 16 + hh * 8);

        // stage ALL of SQF (16384 f32 = 4096 f32x4), coalesced
        {
            const f32x4* src = (const f32x4*)SQF;
            f32x4* dst = (f32x4*)S.knn;
            for (int q = t; q < 4096; q += 512) dst[q] = src[q];
        }

        float g0 = BIGF, g1 = BIGF, g2 = BIGF, g3 = BIGF;
        float g4 = BIGF, g5 = BIGF, g6 = BIGF, g7 = BIGF;
        float g8 = BIGF, g9 = BIGF, g10 = BIGF, g11 = BIGF;

        // wave w sweeps j-window [w*2048, (w+1)*2048): 64 tiles of 32
        const _Float16* pH = H + ((size_t)(w * 2048 + r31)) * 16 + hh * 8;
        const _Float16* pL = L + ((size_t)(w * 2048 + r31)) * 16 + hh * 8;
        const float* sqb = S.knn + w * 2048 + hh * 4;
        unsigned idt = (unsigned)((w << 1) | hh);

        __syncthreads();   // sq staged

#pragma unroll 2
        for (int tt = 0; tt < 64; ++tt) {
            half8 Ah = *(const half8*)(pH + (size_t)tt * 512);
            half8 Al = *(const half8*)(pL + (size_t)tt * 512);
            const f32x4* s_ = (const f32x4*)(sqb + tt * 32);

            C16 c;
            c.q[0] = s_[0]; c.q[1] = s_[2]; c.q[2] = s_[4]; c.q[3] = s_[6];
            c.w = __builtin_amdgcn_mfma_f32_32x32x16_f16(Ah, B1, c.w, 0, 0, 0);
            c.w = __builtin_amdgcn_mfma_f32_32x32x16_f16(Al, B1, c.w, 0, 0, 0);

            float v0 = fminf(fminf(c.w[0], c.w[1]), c.w[2]);
            float v1 = fminf(fminf(c.w[3], c.w[4]), c.w[5]);
            float v2 = fminf(fminf(c.w[6], c.w[7]), c.w[8]);
            float v3 = fminf(fminf(c.w[9], c.w[10]), c.w[11]);
            float v4 = fminf(fminf(c.w[12], c.w[13]), c.w[14]);
            float v5 = fminf(fminf(v0, v1), c.w[15]);
            float v6 = fminf(fminf(v2, v3), v4);
            float vmin = fminf(v5, v6);

            unsigned pk = (__float_as_uint(vmin) & 0xFFFFFC00u)
                        | (idt + (unsigned)(tt << 4));
            float pf = __uint_as_float(pk);
            INS12G(pf);
        }

        MERGE12_SHFL(32);

        __syncthreads();   // sq reads done; S.knn reusable as merge tree

#define STORE12() if (lane < 32) {                           \
            S.knn[(w * GL + 0) * 32 + r31] = g0;             \
            S.knn[(w * GL + 1) * 32 + r31] = g1;             \
            S.knn[(w * GL + 2) * 32 + r31] = g2;             \
            S.knn[(w * GL + 3) * 32 + r31] = g3;             \
            S.knn[(w * GL + 4) * 32 + r31] = g4;             \
            S.knn[(w * GL + 5) * 32 + r31] = g5;             \
            S.knn[(w * GL + 6) * 32 + r31] = g6;             \
            S.knn[(w * GL + 7) * 32 + r31] = g7;             \
            S.knn[(w * GL + 8) * 32 + r31] = g8;             \
            S.knn[(w * GL + 9) * 32 + r31] = g9;             \
            S.knn[(w * GL + 10) * 32 + r31] = g10;           \
            S.knn[(w * GL + 11) * 32 + r31] = g11; }

        if (w >= 4) STORE12();
        __syncthreads();
        if (w < 4) {
            int pw = w + 4;
#define LD(s) S.knn[(pw * GL + (s)) * 32 + r31]
            MERGE12_LDS(LD);
#undef LD
        }
        __syncthreads();
        if (w == 2 || w == 3) STORE12();
        __syncthreads();
        if (w < 2) {
            int pw = w + 2;
#define LD(s) S.knn[(pw * GL + (s)) * 32 + r31]
            MERGE12_LDS(LD);
#undef LD
        }
        __syncthreads();
        if (w == 1) STORE12();
        __syncthreads();
        if (w == 0) {
            int pw = 1;
#define LD(s) S.knn[(pw * GL + (s)) * 32 + r31]
            MERGE12_LDS(LD);
#undef LD
            if (lane < 32) {
                // final top-12 lists -> LDS (no CV global round-trip)
                sList[r31 * GL + 0] = __float_as_uint(g0);
                sList[r31 * GL + 1] = __float_as_uint(g1);
                sList[r31 * GL + 2] = __float_as_uint(g2);
                sList[r31 * GL + 3] = __float_as_uint(g3);
                sList[r31 * GL + 4] = __float_as_uint(g4);
                sList[r31 * GL + 5] = __float_as_uint(g5);
                sList[r31 * GL + 6] = __float_as_uint(g6);
                sList[r31 * GL + 7] = __float_as_uint(g7);
                sList[r31 * GL + 8] = __float_as_uint(g8);
                sList[r31 * GL + 9] = __float_as_uint(g9);
                sList[r31 * GL + 10] = __float_as_uint(g10);
                sList[r31 * GL + 11] = __float_as_uint(g11);
            }
        }
#undef STORE12
    }

    __syncthreads();   // lists final; S.knn free for head weights

    // ================= Phase H: head (32 points, 16 lanes each) ==========
    {
        for (int q = t; q < 16 * 16; q += 512) S.h.we2[q] = We[256 + q];
        for (int q = t; q < 16 * 32; q += 512) S.h.wf1[q] = Wf1[q];
        for (int q = t; q < 32; q += 512) S.h.bf1s[q] = bf1[q];
        for (int q = t; q < 32 * 16; q += 512) S.h.wf2[q] = Wf2[q];
        for (int q = t; q < 16; q += 512) S.h.bf2s[q] = bf2[q];
        if (t < 32) S.h.cnt[t] = 0;
        __syncthreads();

        int l = t & 15;          // lane within point
        int pt = t >> 4;         // point within block (0..31)
        int ql = l & 3;
        int qd = l >> 2;
        int i = i0 + pt;

        float xi[16];
        {
            const f32x4* xiv = (const f32x4*)(x + (size_t)i * 16);
#pragma unroll
            for (int q = 0; q < 4; ++q) {
                f32x4 a = xiv[q];
#pragma unroll
                for (int r = 0; r < 4; ++r) xi[q * 4 + r] = a[r];
            }
        }
        f32x4 xiq = ((const f32x4*)(x + (size_t)i * 16))[ql];

        // scan A: 12 groups x 4 coalesced runs
        float val[12];
        int jbs[12];
        float d0 = BIGF, d1 = BIGF, d2 = BIGF, d3 = BIGF;
        float d4 = BIGF, d5 = BIGF, d6 = BIGF, d7 = BIGF;
#pragma unroll
        for (int g = 0; g < GL; ++g) {
            unsigned id = sList[pt * GL + g] & 0x3FFu;
            int jb = (int)(((id >> 1) & 7) * 2048 + (id >> 4) * 32 + (id & 1) * 4);
            jbs[g] = jb;
            float vg = BIGF;
#pragma unroll
            for (int rho = 0; rho < 4; ++rho) {
                f32x4 a = *((const f32x4*)(x + ((size_t)(jb + rho * 8)) * 16) + l);
                float qdot = xiq[0] * a[0];
                qdot = fmaf(xiq[1], a[1], qdot);
                qdot = fmaf(xiq[2], a[2], qdot);
                qdot = fmaf(xiq[3], a[3], qdot);
                qdot += __shfl_xor(qdot, 1, 64);
                qdot += __shfl_xor(qdot, 2, 64);
                float v = fmaf(qdot, -2.0f, SQF[jb + rho * 8 + qd]);
                vg = (ql == rho) ? v : vg;
            }
            val[g] = vg;
            INS8V(vg);
        }

        // exact kth over the point's 192 candidates (16-lane butterfly)
        MERGE8(1);
        MERGE8(2);
        MERGE8(4);
        MERGE8(8);
        float kth = d7;

        // scan B: register re-scan, collect ids
#pragma unroll
        for (int g = 0; g < GL; ++g) {
            float v = val[g];
            if (v <= kth) {
                int j = jbs[g] + ql * 8 + qd;
                int p = atomicAdd(&S.h.cnt[pt], 1);
                if (p < KNN) S.h.idx[pt * 8 + p] = j;
            }
        }
        __syncthreads();

        int e8 = l & 7;
        int j = S.h.idx[pt * 8 + e8];

        float xd[16];
        {
            const f32x4* xjv = (const f32x4*)(x + (size_t)j * 16);
#pragma unroll
            for (int q = 0; q < 4; ++q) {
                f32x4 a = xjv[q];
#pragma unroll
                for (int r = 0; r < 4; ++r) xd[q * 4 + r] = a[r] - xi[q * 4 + r];
            }
        }

        float acc[16];
        {
            const f32x4* av = (const f32x4*)(ACC + (size_t)i * 16);
#pragma unroll
            for (int q = 0; q < 4; ++q) {
                f32x4 a = av[q];
#pragma unroll
                for (int r = 0; r < 4; ++r) acc[q * 4 + r] = a[r];
            }
        }
#pragma unroll
        for (int d = 0; d < 16; ++d) {
            float v = xd[d];
#pragma unroll
            for (int h = 0; h < 16; ++h) acc[h] += v * S.h.we2[d * 16 + h];
        }

        float feats[16];
#pragma unroll
        for (int h = 0; h < 16; ++h) feats[h] = silu(acc[h]);

#pragma unroll
        for (int mask = 1; mask <= 4; mask <<= 1) {
#pragma unroll
            for (int h = 0; h < 16; ++h) feats[h] += __shfl_xor(feats[h], mask, 64);
        }
#pragma unroll
        for (int h = 0; h < 16; ++h) feats[h] *= 0.125f;

        // f1: lane l computes outputs l and l+16
        float p0 = S.h.bf1s[l];
        float p1 = S.h.bf1s[l + 16];
#pragma unroll
        for (int k = 0; k < 16; ++k) {
            float v = feats[k];
            p0 = fmaf(v, S.h.wf1[k * 32 + l], p0);
            p1 = fmaf(v, S.h.wf1[k * 32 + l + 16], p1);
        }
        p0 = silu(p0);
        p1 = silu(p1);
        S.h.f1[pt * 33 + l] = p0;
        S.h.f1[pt * 33 + 16 + l] = p1;
        __syncthreads();

        // f2: lane l computes output l
        float o = S.h.bf2s[l];
#pragma unroll
        for (int k = 0; k < 32; ++k)
            o = fmaf(S.h.f1[pt * 33 + k], S.h.wf2[k * 16 + l], o);

        out[(size_t)i * 29 + l] = o;
        if (l < DIN) out[(size_t)i * 29 + 16 + l] = x_pfc[i * DIN + l];
    }
}

extern "C" void kernel_launch(void* const* d_in, const int* in_sizes, int n_in,
                              void* d_out, int out_size, void* d_ws, size_t ws_size,
                              hipStream_t stream)
{
    const float* x_pfc = (const float*)d_in[0];
    const float* W1 = (const float*)d_in[1];
    const float* b1 = (const float*)d_in[2];
    const float* W2 = (const float*)d_in[3];
    const float* b2 = (const float*)d_in[4];
    const float* W3 = (const float*)d_in[5];
    const float* b3 = (const float*)d_in[6];
    const float* We = (const float*)d_in[7];
    const float* be = (const float*)d_in[8];
    const float* Wf1 = (const float*)d_in[9];
    const float* bf1 = (const float*)d_in[10];
    const float* Wf2 = (const float*)d_in[11];
    const float* bf2 = (const float*)d_in[12];
    float* out = (float*)d_out;

    float* xw = (float*)d_ws;                         // N*16 f32
    float* ACCa = xw + (size_t)NPTS * 16;             // N*16 f32
    _Float16* Ha = (_Float16*)(ACCa + (size_t)NPTS * 16);  // N*16 f16
    _Float16* La = Ha + (size_t)NPTS * 16;
    _Float16* YHa = La + (size_t)NPTS * 16;
    float* SQFa = (float*)(YHa + (size_t)NPTS * 16);  // N f32

    hipLaunchKernelGGL(k_encoder, dim3(NPTS / 64), dim3(64), 0, stream,
                       x_pfc, W1, b1, W2, b2, W3, b3, We, be,
                       xw, Ha, La, YHa, SQFa, ACCa);
    hipLaunchKernelGGL(k_knn_head, dim3(NPTS / 32), dim3(512), 0, stream,
                       Ha, La, YHa, SQFa, xw, x_pfc, ACCa,
                       We, Wf1, bf1, Wf2, bf2, out);
}